// Round 4
// baseline (367.185 us; speedup 1.0000x reference)
//
#include <hip/hip_runtime.h>
#include <cmath>
#include <cstddef>

#define BATCH 8
#define CH    3
#define HH    512
#define WW    512
#define NSLOT 7
#define HWX   (HH*WW)

__device__ __host__ __forceinline__ int refl(int i, int n) {
    i = i < 0 ? -i : i;
    return i >= n ? 2 * n - 2 - i : i;
}

// ---------------- compile-time Gaussian weights -----------------
constexpr double cexp_(double x) {           // e^x for x in [-13, 0]
    double r = x / 64.0, term = 1.0, s = 1.0;
    for (int i = 1; i < 26; ++i) { term *= r / i; s += term; }
    for (int j = 0; j < 6; ++j) s *= s;      // s = (e^{x/64})^64
    return s;
}

// h-pass weights: effective size KSE = KS + Z (Z zero taps prepended so the
// staged row's left pad is a multiple of 4 floats -> all-b128 LDS staging).
// Real taps at [8+Z, 8+KSE), zeros elsewhere; compile-time indexed -> literals.
template<int KSE> struct WArr { float w[KSE + 16]; };

template<int KSE, int KS>
constexpr WArr<KSE> make_wz(double sg) {
    WArr<KSE> a{};
    double tmp[KS] = {};
    double sum = 0.0;
    for (int t = 0; t < KS; ++t) {
        const double ax = (double)(t - KS / 2);
        tmp[t] = cexp_(-(ax * ax) / (2.0 * sg * sg));
        sum += tmp[t];
    }
    for (int i = 0; i < KSE + 16; ++i) a.w[i] = 0.0f;
    constexpr int Z = KSE - KS;
    for (int t = 0; t < KS; ++t) a.w[8 + Z + t] = (float)(tmp[t] / sum);
    return a;
}

// per scale: KS {7,9,17,31,59,117}, PD=KS/2 {3,4,8,15,29,58}
// PDA = round-up-4 {4,4,8,16,32,60}; Z = PDA-PD {1,0,0,1,3,2}; KSE = KS+Z
__device__ constexpr WArr<8>   CW0 = make_wz<8,   7>(0.6);
__device__ constexpr WArr<9>   CW1 = make_wz<9,   9>(1.2);
__device__ constexpr WArr<17>  CW2 = make_wz<17, 17>(2.4);
__device__ constexpr WArr<32>  CW3 = make_wz<32, 31>(4.8);
__device__ constexpr WArr<62>  CW4 = make_wz<62, 59>(9.6);
__device__ constexpr WArr<119> CW5 = make_wz<119,117>(19.2);

// v-pass weights: 16 leading zeros, taps at [16,16+KS), zero-padded to TPAD+16
template<int KS> struct VWArr {
    static constexpr int TPAD = (KS + 30) & ~15;
    float w[TPAD + 16];
};

template<int KS>
constexpr VWArr<KS> make_vw(double sg) {
    VWArr<KS> a{};
    double tmp[KS] = {};
    double sum = 0.0;
    for (int t = 0; t < KS; ++t) {
        const double ax = (double)(t - KS / 2);
        tmp[t] = cexp_(-(ax * ax) / (2.0 * sg * sg));
        sum += tmp[t];
    }
    for (int i = 0; i < VWArr<KS>::TPAD + 16; ++i) a.w[i] = 0.0f;
    for (int t = 0; t < KS; ++t) a.w[16 + t] = (float)(tmp[t] / sum);
    return a;
}

__device__ constexpr VWArr<7>   VW0 = make_vw<7>(0.6);
__device__ constexpr VWArr<9>   VW1 = make_vw<9>(1.2);
__device__ constexpr VWArr<17>  VW2 = make_vw<17>(2.4);
__device__ constexpr VWArr<31>  VW3 = make_vw<31>(4.8);
__device__ constexpr VWArr<59>  VW4 = make_vw<59>(9.6);
__device__ constexpr VWArr<117> VW5 = make_vw<117>(19.2);

// ---------------- vertical blur: 16 rows x float4 per thread ----------------
template<int KS, int PD>
__device__ __forceinline__ void vpass16(const float4* __restrict__ img4,
                                        float4* __restrict__ dst,
                                        int xt, int y0, const float* __restrict__ vw)
{
    constexpr int TPAD = (KS + 30) & ~15;
    float4 acc[16];
#pragma unroll
    for (int j = 0; j < 16; ++j) acc[j] = make_float4(0.f, 0.f, 0.f, 0.f);

    float ww[16];                      // window low half: ww[m] == vw[tb+m]
#pragma unroll
    for (int m = 0; m < 16; ++m) ww[m] = vw[m];

#pragma unroll 1
    for (int tb = 0; tb < TPAD; tb += 16) {
        float wn[16];                  // window high half: wn[k] == vw[tb+16+k]
#pragma unroll
        for (int k = 0; k < 16; ++k) wn[k] = vw[tb + 16 + k];
#pragma unroll
        for (int k = 0; k < 16; ++k) {
            const int yi = refl(y0 - PD + tb + k, HH);
            const float4 v = img4[(size_t)yi * (WW / 4) + xt];
#pragma unroll
            for (int j = 0; j < 16; ++j) {
                const int mi = 16 + k - j;               // 1..31, compile-time
                const float wt = (mi < 16) ? ww[mi] : wn[mi - 16];
                acc[j].x = fmaf(wt, v.x, acc[j].x);
                acc[j].y = fmaf(wt, v.y, acc[j].y);
                acc[j].z = fmaf(wt, v.z, acc[j].z);
                acc[j].w = fmaf(wt, v.w, acc[j].w);
            }
        }
#pragma unroll
        for (int m = 0; m < 16; ++m) ww[m] = wn[m];      // shift window
    }
#pragma unroll
    for (int j = 0; j < 16; ++j) dst[(size_t)(y0 + j) * (WW / 4) + xt] = acc[j];
}

// 1-D grid, XCD-swizzled: n = k*8 + xcd; per-XCD phase works on ONE channel
// image (1 MB) -> img re-reads hit that XCD's 4 MB L2 instead of streaming L3.
// 4608 = 8 xcd * 3 bcg * (6 scales * 32 ygroups)
__global__ __launch_bounds__(128) void vpass6_kernel(const float* __restrict__ img,
                                                     float* __restrict__ out)
{
    const int n   = blockIdx.x;
    const int xcd = n & 7;
    const int k   = n >> 3;              // 0..575
    const int bcg = k / 192;             // 0..2
    const int rem = k - bcg * 192;
    const int s   = rem >> 5;            // 0..5
    const int y0  = (rem & 31) << 4;
    const int bc  = bcg * 8 + xcd;       // 0..23
    const int xt  = threadIdx.x;         // 0..127 (float4 col)
    const int b = bc / CH, c = bc - b * CH;
    const float4* img4 = (const float4*)img + (size_t)bc * (HWX / 4);
    float4* dst = (float4*)out + ((size_t)((b * NSLOT + s + 1) * CH) + c) * (HWX / 4);
    switch (s) {
        case 0: vpass16<  7,  3>(img4, dst, xt, y0, VW0.w); break;
        case 1: vpass16<  9,  4>(img4, dst, xt, y0, VW1.w); break;
        case 2: vpass16< 17,  8>(img4, dst, xt, y0, VW2.w); break;
        case 3: vpass16< 31, 15>(img4, dst, xt, y0, VW3.w); break;
        case 4: vpass16< 59, 29>(img4, dst, xt, y0, VW4.w); break;
        default:vpass16<117, 58>(img4, dst, xt, y0, VW5.w); break;
    }
}

// ---------------- horizontal blur: 8 px/thread, 6-slot rolling window -----------------------
// 64 threads (u=0..63) own a full row, 8 px each. Reads: slots 2u..2u+G+1 (G+2 b128 per
// thread => total LDS read instrs HALVED vs 4px/thread; pixel-wise FMA order unchanged).
template<int KSE>
__device__ __forceinline__ void hblur8(const float* __restrict__ lrow, int u,
                                       const WArr<KSE>& W, float* __restrict__ a)
{
    constexpr int NT = (KSE + 3) & ~3;
    constexpr int G  = NT / 4;           // tap groups
    constexpr int NR = G + 2;            // float4 slots needed: 2u .. 2u+G+1
    const float4* l4 = (const float4*)lrow;
    float cb[24];                        // 6 rolling float4 slots
#pragma unroll
    for (int s = 0; s < 4; ++s) {        // up-front prefetch (NR >= 4 for all scales)
        const float4 t = l4[2 * u + s];
        cb[s * 4 + 0] = t.x; cb[s * 4 + 1] = t.y;
        cb[s * 4 + 2] = t.z; cb[s * 4 + 3] = t.w;
    }
#pragma unroll
    for (int j = 0; j < 8; ++j) a[j] = 0.f;
#pragma unroll
    for (int g = 0; g < G; ++g) {
        if (g + 4 < NR) {                // read ahead (folds at unroll)
            const int sl = (g + 4) % 6;
            const float4 t = l4[2 * u + g + 4];
            cb[sl * 4 + 0] = t.x; cb[sl * 4 + 1] = t.y;
            cb[sl * 4 + 2] = t.z; cb[sl * 4 + 3] = t.w;
        }
#pragma unroll
        for (int tt = 0; tt < 4; ++tt) {
            const float wt = W.w[8 + 4 * g + tt];        // compile-time constant
#pragma unroll
            for (int j = 0; j < 8; ++j) {
                const int q    = tt + j;                 // 0..10
                const int slot = (g + (q >> 2)) % 6;     // 3 live slots per group
                a[j] = fmaf(wt, cb[slot * 4 + (q & 3)], a[j]);
            }
        }
    }
}

// ---------------- fused h-pass + DoG diff, in-place on out ---------------------------------
// Two rows per 128-thread block (threads 0-63 -> row y, 64-127 -> row y+1).
// LDS layout per row (floats), left pad PDA (mult of 4):
// s:      0     1     2     3     4     5
// PDA:    4     4     8    16    32    60
// OFF:    0   524  1052  1588  2136  2716
// LEN:  524   528   536   548   580   636   (= NT + 516)
#define LDSROW 3352   // 2 rows = 26816 B/block -> 6 blocks/CU (12 waves)

// All-vector staging by 64 threads: two b128 bulk stores + tiny scalar halos.
template<int OFF, int LEN, int PDA>
__device__ __forceinline__ void stage_row8(float* __restrict__ L,
                                           const float* __restrict__ g, int u)
{
    ((float4*)(L + OFF + PDA))[u]      = ((const float4*)g)[u];
    ((float4*)(L + OFF + PDA))[u + 64] = ((const float4*)g)[u + 64];
    if (u < PDA) L[OFF + u] = g[PDA - u];                         // left reflect
    for (int i = PDA + 512 + u; i < LEN; i += 64)                 // right reflect
        L[OFF + i] = g[1022 - (i - PDA)];
}

// 1-D grid, XCD-swizzled consistently with vpass (same bc -> same XCD).
// Per dispatch: 3072 = 8 xcd * 3 bcg * 128 row-pairs (grid split in two so each
// hdiff dispatch drops below vpass6 and vpass6 surfaces in the profile top-5).
__global__ __launch_bounds__(128) void hdiff6_kernel(const float* __restrict__ img,
                                                     float* __restrict__ out, int ybase)
{
    __shared__ __align__(16) float lds[2][LDSROW];
    const int xt  = threadIdx.x;         // 0..127
    const int u   = xt & 63;             // lane within row
    const int r   = xt >> 6;             // row within block
    const int n   = blockIdx.x;
    const int xcd = n & 7;
    const int k   = n >> 3;              // 0..383
    const int bcg = k >> 7;              // 0..2
    const int yp  = k & 127;
    const int y   = ybase + yp * 2 + r;
    const int bc  = bcg * 8 + xcd;       // 0..23
    const int b = bc / CH, c = bc - b * CH;
    float* L = lds[r];

    const size_t rowoff = (size_t)y * WW;
    // g0 = img row, own 8 px; issue before the barrier so it overlaps staging
    const float4* ib = (const float4*)(img + (size_t)bc * HWX + rowoff);
    const float4 gpa = ib[2 * u], gpb = ib[2 * u + 1];
    float gp[8] = {gpa.x, gpa.y, gpa.z, gpa.w, gpb.x, gpb.y, gpb.z, gpb.w};

    // stage the 6 v-blurred rows from out slots 1..6
    constexpr size_t SSTR = (size_t)CH * HWX;     // slot stride in floats
    const float* g1 = out + ((size_t)((b * NSLOT + 1) * CH) + c) * HWX + rowoff;
    stage_row8<   0, 524,  4>(L, g1,            u);
    stage_row8< 524, 528,  4>(L, g1 + 1 * SSTR, u);
    stage_row8<1052, 536,  8>(L, g1 + 2 * SSTR, u);
    stage_row8<1588, 548, 16>(L, g1 + 3 * SSTR, u);
    stage_row8<2136, 580, 32>(L, g1 + 4 * SSTR, u);
    stage_row8<2716, 636, 60>(L, g1 + 5 * SSTR, u);
    __syncthreads();

    float4* out4 = (float4*)out;
    const size_t pbase = (size_t)y * (WW / 4) + 2 * u;
#define OSL(s) (out4 + ((size_t)((b * NSLOT + (s)) * CH) + c) * (HWX / 4) + pbase)

    float gcur[8];
#define EMIT(s, OFF, CW)                                                        \
    {                                                                           \
        hblur8<sizeof(CW.w)/4 - 16>(L + OFF, u, CW, gcur);                      \
        float4* o = OSL(s);                                                     \
        o[0] = make_float4(gcur[0]-gp[0], gcur[1]-gp[1], gcur[2]-gp[2], gcur[3]-gp[3]); \
        o[1] = make_float4(gcur[4]-gp[4], gcur[5]-gp[5], gcur[6]-gp[6], gcur[7]-gp[7]); \
        _Pragma("unroll")                                                       \
        for (int j = 0; j < 8; ++j) gp[j] = gcur[j];                            \
    }

    EMIT(0,    0, CW0);
    EMIT(1,  524, CW1);
    EMIT(2, 1052, CW2);
    EMIT(3, 1588, CW3);
    EMIT(4, 2136, CW4);
    EMIT(5, 2716, CW5);
    {   // slot 6 = last gaussian itself
        float4* o = OSL(6);
        o[0] = make_float4(gp[0], gp[1], gp[2], gp[3]);
        o[1] = make_float4(gp[4], gp[5], gp[6], gp[7]);
    }
#undef EMIT
#undef OSL
}

// ---------------- host ----------------------------------------------------------------------
extern "C" void kernel_launch(void* const* d_in, const int* in_sizes, int n_in,
                              void* d_out, int out_size, void* d_ws, size_t ws_size,
                              hipStream_t stream) {
    const float* img = (const float*)d_in[0];
    float* out = (float*)d_out;

    // pass 1: vertical blur img -> out slots 1..6 (XCD-swizzled 1-D grid)
    hipLaunchKernelGGL(vpass6_kernel, dim3(4608), dim3(128), 0, stream, img, out);

    // pass 2: horizontal blur + DoG diff chain, in-place on out (XCD-swizzled,
    // split into two half-grid dispatches for per-dispatch profiling visibility)
    hipLaunchKernelGGL(hdiff6_kernel, dim3(3072), dim3(128), 0, stream, img, out, 0);
    hipLaunchKernelGGL(hdiff6_kernel, dim3(3072), dim3(128), 0, stream, img, out, 256);
}